// Round 1
// baseline (114.355 us; speedup 1.0000x reference)
//
#include <hip/hip_runtime.h>
#include <hip/hip_bf16.h>

#define B_ 128
#define T_ 256
#define D_ 1024
#define L_ 48
#define SMALL_ (-1000.0f)

typedef float f32x4 __attribute__((ext_vector_type(4)));
typedef short bf16x8 __attribute__((ext_vector_type(8)));

__device__ __forceinline__ short f2bf(float f) {
    unsigned u = __float_as_uint(f);
    unsigned r = (u + 0x7FFFu + ((u >> 16) & 1u)) >> 16;
    return (short)r;
}

__device__ __forceinline__ float bcast(float v, int lane) {
    return __uint_as_float(__builtin_amdgcn_readlane(__float_as_uint(v), lane));
}

// ---------- Kernel 1: W f32 -> bf16 ----------
__global__ __launch_bounds__(256) void wconv_kernel(const float* __restrict__ W,
                                                    unsigned short* __restrict__ wbf) {
    int i = blockIdx.x * 256 + threadIdx.x;  // grid covers 48*1024 = 49152
    unsigned u = __float_as_uint(W[i]);
    wbf[i] = (unsigned short)((u + 0x7FFFu + ((u >> 16) & 1u)) >> 16);
}

// ---------- Kernel 2: pred = x @ W^T + b  via bf16 MFMA, no LDS ----------
__global__ __launch_bounds__(256) void gemm_kernel(const float* __restrict__ x,
                                                   const unsigned short* __restrict__ wbf,
                                                   const float* __restrict__ bias,
                                                   float* __restrict__ pred) {
    const int wave = threadIdx.x >> 6;
    const int lane = threadIdx.x & 63;
    const int m0 = blockIdx.x * 64 + wave * 16;   // grid 512 blocks -> 32768 rows
    const int l16 = lane & 15;
    const int lg  = lane >> 4;                     // k-group 0..3

    const float* xrow = x + (size_t)(m0 + l16) * D_ + lg * 8;
    f32x4 acc0 = {0.f,0.f,0.f,0.f}, acc1 = {0.f,0.f,0.f,0.f}, acc2 = {0.f,0.f,0.f,0.f};

    #pragma unroll 4
    for (int k0 = 0; k0 < D_; k0 += 32) {
        float4 xa = *reinterpret_cast<const float4*>(xrow + k0);
        float4 xb = *reinterpret_cast<const float4*>(xrow + k0 + 4);
        bf16x8 af;
        af[0] = f2bf(xa.x); af[1] = f2bf(xa.y); af[2] = f2bf(xa.z); af[3] = f2bf(xa.w);
        af[4] = f2bf(xb.x); af[5] = f2bf(xb.y); af[6] = f2bf(xb.z); af[7] = f2bf(xb.w);
        const unsigned short* wp = wbf + (size_t)l16 * D_ + k0 + lg * 8;
        bf16x8 b0 = *reinterpret_cast<const bf16x8*>(wp);
        bf16x8 b1 = *reinterpret_cast<const bf16x8*>(wp + 16 * D_);
        bf16x8 b2 = *reinterpret_cast<const bf16x8*>(wp + 32 * D_);
        acc0 = __builtin_amdgcn_mfma_f32_16x16x32_bf16(af, b0, acc0, 0, 0, 0);
        acc1 = __builtin_amdgcn_mfma_f32_16x16x32_bf16(af, b1, acc1, 0, 0, 0);
        acc2 = __builtin_amdgcn_mfma_f32_16x16x32_bf16(af, b2, acc2, 0, 0, 0);
    }

    // C layout (verified): col = lane&15, row = (lane>>4)*4 + reg
    const int rbase = m0 + lg * 4;
    float bi0 = bias[l16], bi1 = bias[16 + l16], bi2 = bias[32 + l16];
    #pragma unroll
    for (int r = 0; r < 4; ++r) {
        size_t ro = (size_t)(rbase + r) * L_;
        pred[ro + l16]      = acc0[r] + bi0;
        pred[ro + 16 + l16] = acc1[r] + bi1;
        pred[ro + 32 + l16] = acc2[r] + bi2;
    }
}

// ---------- Kernel 3: CRF forward recursion + gold score, one wave per batch ----------
__global__ __launch_bounds__(64) void crf_kernel(const float* __restrict__ pred,
                                                 const float* __restrict__ trans,
                                                 const int* __restrict__ tags,
                                                 const int* __restrict__ seq_len,
                                                 float* __restrict__ res) {
    const int b = blockIdx.x;
    const int j = threadIdx.x;        // lane
    const int jj = (j < L_) ? j : (L_ - 1);
    const int n = seq_len[b];         // 1..256

    // E column: E[i] = exp(trans[i][jj])
    float E[48];
    #pragma unroll
    for (int i = 0; i < 48; ++i) E[i] = __expf(trans[i * L_ + jj]);

    const int* tg = tags + b * T_;
    const float* pb = pred + (size_t)b * T_ * L_;

    // ---- gold-path score (lane-parallel over t) ----
    float sc = 0.f;
    for (int t = j; t < n; t += 64) {
        int tag = tg[t];
        int pt = (t == 0) ? (L_ - 2) : tg[t - 1];
        sc += pb[t * L_ + tag] + trans[pt * L_ + tag];
    }
    if (j == 0) sc += trans[tg[n - 1] * L_ + (L_ - 1)];
    #pragma unroll
    for (int o = 32; o > 0; o >>= 1) sc += __shfl_xor(sc, o, 64);

    // ---- forward recursion ----
    // a = alpha' (normalized), M = running offset.  exp(-1000) == 0 in f32.
    float a = (j == (L_ - 2)) ? 0.f : SMALL_;
    float M = 0.f;
    float e = (j < L_ - 2) ? pb[j] : SMALL_;   // emission for step 1 (t=0)

    for (int s = 1; s <= n; ++s) {
        float e_next = SMALL_;
        if (s < n && j < L_ - 2) e_next = pb[s * L_ + j];   // prefetch

        float p = __expf(a);
        float a0 = 0.f, a1 = 0.f, a2 = 0.f, a3 = 0.f;
        #pragma unroll
        for (int i = 0; i < 48; i += 4) {
            a0 = fmaf(bcast(p, i + 0), E[i + 0], a0);
            a1 = fmaf(bcast(p, i + 1), E[i + 1], a1);
            a2 = fmaf(bcast(p, i + 2), E[i + 2], a2);
            a3 = fmaf(bcast(p, i + 3), E[i + 3], a3);
        }
        float raw = (a0 + a1) + (a2 + a3);
        float t_ = __logf(raw) + e;
        float r = bcast(t_, 0);     // lane-0 shift: always a finite emission column
        a = t_ - r;
        M += r;
        e = e_next;
    }

    // final transition-to-end step (emission: 0 at L-1, SMALL elsewhere)
    {
        float p = __expf(a);
        float a0 = 0.f, a1 = 0.f, a2 = 0.f, a3 = 0.f;
        #pragma unroll
        for (int i = 0; i < 48; i += 4) {
            a0 = fmaf(bcast(p, i + 0), E[i + 0], a0);
            a1 = fmaf(bcast(p, i + 1), E[i + 1], a1);
            a2 = fmaf(bcast(p, i + 2), E[i + 2], a2);
            a3 = fmaf(bcast(p, i + 3), E[i + 3], a3);
        }
        float raw = (a0 + a1) + (a2 + a3);
        float e_fin = (j == (L_ - 1)) ? 0.f : SMALL_;
        float t_ = __logf(raw) + e_fin;

        float m2 = t_;
        #pragma unroll
        for (int o = 32; o > 0; o >>= 1) m2 = fmaxf(m2, __shfl_xor(m2, o, 64));
        float ex = __expf(t_ - m2);
        #pragma unroll
        for (int o = 32; o > 0; o >>= 1) ex += __shfl_xor(ex, o, 64);
        float logz = M + m2 + __logf(ex);

        if (j == 0) res[b] = logz - sc;
    }
}

// ---------- Kernel 4: deterministic 128 -> 1 reduce ----------
__global__ __launch_bounds__(128) void reduce_kernel(const float* __restrict__ res,
                                                     float* __restrict__ out) {
    int t = threadIdx.x;
    float v = res[t];
    #pragma unroll
    for (int o = 32; o > 0; o >>= 1) v += __shfl_xor(v, o, 64);
    __shared__ float sm[2];
    if ((t & 63) == 0) sm[t >> 6] = v;
    __syncthreads();
    if (t == 0) out[0] = sm[0] + sm[1];
}

extern "C" void kernel_launch(void* const* d_in, const int* in_sizes, int n_in,
                              void* d_out, int out_size, void* d_ws, size_t ws_size,
                              hipStream_t stream) {
    const float* x      = (const float*)d_in[0];
    const float* W      = (const float*)d_in[1];
    const float* bias   = (const float*)d_in[2];
    const float* trans  = (const float*)d_in[3];
    const int*   tags   = (const int*)d_in[4];
    const int*   seqlen = (const int*)d_in[5];
    float* out = (float*)d_out;

    // workspace layout
    float* pred = (float*)d_ws;                                      // 32768*48*4 = 6291456 B
    unsigned short* wbf = (unsigned short*)((char*)d_ws + 6291456);  // 49152*2 = 98304 B
    float* res = (float*)((char*)d_ws + 6389760);                    // 128*4 B

    hipLaunchKernelGGL(wconv_kernel, dim3(192), dim3(256), 0, stream, W, wbf);
    hipLaunchKernelGGL(gemm_kernel, dim3(512), dim3(256), 0, stream, x, wbf, bias, pred);
    hipLaunchKernelGGL(crf_kernel, dim3(B_), dim3(64), 0, stream, pred, trans, tags, seqlen, res);
    hipLaunchKernelGGL(reduce_kernel, dim3(1), dim3(128), 0, stream, res, out);
}